// Round 14
// baseline (322.125 us; speedup 1.0000x reference)
//
#include <hip/hip_runtime.h>
#include <math.h>

#define NN 100000
#define NE 600000
#define DIM 128
#define SEG 1024
#define NSEG 98    // ceil(100000/1024)
#define PBLK 2048  // pooled-agg grid

typedef __attribute__((ext_vector_type(8))) short short8;
typedef __attribute__((ext_vector_type(4))) float floatx4;

// bf16 helpers (RNE)
static __device__ __forceinline__ unsigned short f2bf(float f) {
    union { float f; unsigned u; } v; v.f = f;
    unsigned r = v.u + 0x7fffu + ((v.u >> 16) & 1u);
    return (unsigned short)(r >> 16);
}
static __device__ __forceinline__ float bflo(unsigned int p) {
    union { unsigned u; float f; } v; v.u = p << 16; return v.f;
}
static __device__ __forceinline__ float bfhi(unsigned int p) {
    union { unsigned u; float f; } v; v.u = p & 0xffff0000u; return v.f;
}

// ---------------- MFMA GEMM tile (LDS coalesced staging — R10/R12 proven) ----------------
template <bool A_IS_F32>
static __device__ void gemm_tile(const void* __restrict__ Ain,
                                 const unsigned short* __restrict__ Wp,
                                 unsigned short* __restrict__ H, int n, int tb) {
    __shared__ __align__(16) unsigned short As[64][136];
    const int t = threadIdx.x;
    const int wid = t >> 6, lane = t & 63;
    const int wy = wid & 1, wx = wid >> 1;
    const int base = tb * 64;

    short8 Bf[4][4];
    {
        const short8* wp8 = (const short8*)Wp;
#pragma unroll
        for (int tt = 0; tt < 4; ++tt)
#pragma unroll
            for (int kk = 0; kk < 4; ++kk)
                Bf[tt][kk] = wp8[(((wx * 4 + tt) * 4 + kk) * 64) + lane];
    }

    if constexpr (A_IS_F32) {
        const float* A = (const float*)Ain;
#pragma unroll
        for (int it = 0; it < 8; ++it) {
            int idx = it * 256 + t;
            int row = idx >> 5, seg = idx & 31;
            int r = base + row;
            float4 v = make_float4(0.f, 0.f, 0.f, 0.f);
            if (r < n) v = ((const float4*)(A + (size_t)r * DIM))[seg];
            ushort4 o;
            o.x = f2bf(v.x); o.y = f2bf(v.y); o.z = f2bf(v.z); o.w = f2bf(v.w);
            *((ushort4*)&As[row][seg * 4]) = o;
        }
    } else {
        const unsigned short* A = (const unsigned short*)Ain;
#pragma unroll
        for (int it = 0; it < 4; ++it) {
            int idx = it * 256 + t;
            int row = idx >> 4, seg = idx & 15;
            int r = base + row;
            uint4 v = make_uint4(0, 0, 0, 0);
            if (r < n) v = ((const uint4*)(A + (size_t)r * DIM))[seg];
            *((uint4*)&As[row][seg * 8]) = v;
        }
    }
    __syncthreads();

    floatx4 acc[2][4];
#pragma unroll
    for (int rs = 0; rs < 2; ++rs)
#pragma unroll
        for (int tt = 0; tt < 4; ++tt) acc[rs][tt] = (floatx4){0.f, 0.f, 0.f, 0.f};

    const int m = lane & 15, q = lane >> 4;
#pragma unroll
    for (int rs = 0; rs < 2; ++rs) {
        const int rbase = wy * 32 + rs * 16 + m;
        short8 Af[4];
#pragma unroll
        for (int kk = 0; kk < 4; ++kk)
            Af[kk] = *((const short8*)&As[rbase][kk * 32 + q * 8]);
#pragma unroll
        for (int kk = 0; kk < 4; ++kk)
#pragma unroll
            for (int tt = 0; tt < 4; ++tt)
                acc[rs][tt] = __builtin_amdgcn_mfma_f32_16x16x32_bf16(Af[kk], Bf[tt][kk],
                                                                     acc[rs][tt], 0, 0, 0);
    }
    __syncthreads();

#pragma unroll
    for (int rs = 0; rs < 2; ++rs)
#pragma unroll
        for (int tt = 0; tt < 4; ++tt) {
            const int col = wx * 64 + tt * 16 + m;
            const int rowb = wy * 32 + rs * 16 + q * 4;
#pragma unroll
            for (int i = 0; i < 4; ++i)
                As[rowb + i][col] = f2bf(acc[rs][tt][i]);
        }
    __syncthreads();
#pragma unroll
    for (int it = 0; it < 4; ++it) {
        int idx = it * 256 + t;
        int row = idx >> 4, seg = idx & 15;
        int r = base + row;
        if (r < n)
            ((uint4*)(H + (size_t)r * DIM))[seg] = *((const uint4*)&As[row][seg * 8]);
    }
}

// ---------------- K_init: zero counts + out, pack W0/W1/W2 ----------------
__global__ __launch_bounds__(256) void k_init(int* __restrict__ counts,
                                              const float* __restrict__ W0,
                                              const float* __restrict__ W1,
                                              const float* __restrict__ W2,
                                              unsigned short* __restrict__ Wp,
                                              float* __restrict__ out) {
    const int bid = blockIdx.x, t = threadIdx.x;
    if (bid < 99) {
        const int base = bid * 1024 + t * 4;
#pragma unroll
        for (int i = 0; i < 4; ++i)
            if (base + i < NN + 1) counts[base + i] = 0;
        if (bid == 0 && t < 24) out[t] = 0.f;
    } else {
        const int wb = bid - 99;
        const int which = wb >> 6;
        const float* W = which == 0 ? W0 : (which == 1 ? W1 : W2);
        unsigned short* dst = Wp + which * 16384;
        int e = (wb & 63) * 256 + t;
        int j  = e & 7;
        int L  = (e >> 3) & 63;
        int kk = (e >> 9) & 3;
        int ct = e >> 11;
        int k = kk * 32 + (L >> 4) * 8 + j;
        int c = ct * 16 + (L & 15);
        dst[e] = f2bf(W[k * DIM + c]);
    }
}

// ---------------- standalone edge histogram (2 edges/thread) ----------------
__global__ __launch_bounds__(256) void k_hist(const int* __restrict__ col,
                                              int* __restrict__ counts, int E) {
    int e = (blockIdx.x * 256 + threadIdx.x) * 2;
    if (e + 1 < E) {
        int2 c2 = *(const int2*)(col + e);
        atomicAdd(&counts[c2.x], 1);
        atomicAdd(&counts[c2.y], 1);
    } else if (e < E) {
        atomicAdd(&counts[col[e]], 1);
    }
}

// ---------------- scan phase 1 + fused dinv ----------------
__global__ __launch_bounds__(256) void k_scan1(int* __restrict__ data, int* __restrict__ segsum,
                                               float* __restrict__ dinv, int n) {
    __shared__ int s[256];
    const int t = threadIdx.x;
    const int base = blockIdx.x * SEG + t * 4;
    int v[4];
#pragma unroll
    for (int i = 0; i < 4; ++i) v[i] = (base + i < n) ? data[base + i] : 0;
#pragma unroll
    for (int i = 0; i < 4; ++i)
        if (base + i < n) dinv[base + i] = rsqrtf((float)v[i] + 1.0f);
    int tsum = v[0] + v[1] + v[2] + v[3];
    s[t] = tsum;
    __syncthreads();
    for (int off = 1; off < 256; off <<= 1) {
        int x = (t >= off) ? s[t - off] : 0;
        __syncthreads();
        s[t] += x;
        __syncthreads();
    }
    int run = s[t] - tsum;
#pragma unroll
    for (int i = 0; i < 4; ++i) {
        if (base + i < n) data[base + i] = run;
        run += v[i];
    }
    if (t == 255) segsum[blockIdx.x] = s[255];
}

// ---------------- scan phases 2+3 merged ----------------
__global__ __launch_bounds__(256) void k_scan23(int* __restrict__ offsets,
                                                const int* __restrict__ segsum,
                                                int* __restrict__ cursor, int n) {
    __shared__ int ss[NSEG];
    __shared__ int myoff_s, total_s;
    const int t = threadIdx.x;
    if (t < NSEG) ss[t] = segsum[t];
    __syncthreads();
    if (t == 0) {
        int run = 0;
#pragma unroll 7
        for (int i = 0; i < NSEG; ++i) {
            if (i == (int)blockIdx.x) myoff_s = run;
            run += ss[i];
        }
        total_s = run;
    }
    __syncthreads();
    const int so = myoff_s;
    const int base = blockIdx.x * SEG + t * 4;
#pragma unroll
    for (int i = 0; i < 4; ++i) {
        if (base + i < n) {
            int o = offsets[base + i] + so;
            offsets[base + i] = o;
            cursor[base + i] = o;
        }
    }
    if (blockIdx.x == 0 && t == 0) offsets[n] = total_s;
}

// ---------------- standalone CSR fill ----------------
__global__ __launch_bounds__(256) void k_fill(const int* __restrict__ rows,
                                              const int* __restrict__ cols,
                                              const float* __restrict__ dinv,
                                              int* __restrict__ cursor,
                                              int2* __restrict__ adjw, int E) {
    int e = blockIdx.x * 256 + threadIdx.x;
    if (e < E) {
        int r = rows[e];
        int c = cols[e];
        int pos = atomicAdd(&cursor[c], 1);
        adjw[pos] = make_int2(r, __float_as_int(dinv[r] * dinv[c]));
    }
}

// ---------------- standalone GEMMs ----------------
__global__ __launch_bounds__(256) void k_gemm0(const float* __restrict__ x,
                                               const unsigned short* __restrict__ Wp,
                                               unsigned short* __restrict__ H, int n) {
    gemm_tile<true>((const void*)x, Wp, H, n, blockIdx.x);
}

__global__ __launch_bounds__(256) void k_gemm(const unsigned short* __restrict__ A,
                                              const unsigned short* __restrict__ Wp,
                                              unsigned short* __restrict__ H, int n) {
    gemm_tile<false>((const void*)A, Wp, H, n, blockIdx.x);
}

// ---------------- quarter-wave-per-node CSR aggregation (self + bias + ELU) ----------------
__global__ __launch_bounds__(256) void k_agg2(const unsigned short* __restrict__ H,
                                              const int* __restrict__ offsets,
                                              const int2* __restrict__ adjw,
                                              const float* __restrict__ dinv,
                                              const float* __restrict__ b,
                                              unsigned short* __restrict__ AGG, int n) {
    const int lane = threadIdx.x & 63;
    const int qw = lane >> 4, ql = lane & 15;
    const int p = (blockIdx.x * blockDim.x + threadIdx.x) >> 6;
    const int c = p * 4 + qw;
    if (c >= n) return;
    const float4 bb0 = ((const float4*)b)[ql * 2];
    const float4 bb1 = ((const float4*)b)[ql * 2 + 1];
    float s = dinv[c];
    s = s * s;
    uint4 hv = *(const uint4*)(H + (size_t)c * DIM + ql * 8);
    float a0 = bb0.x + bflo(hv.x) * s;
    float a1 = bb0.y + bfhi(hv.x) * s;
    float a2 = bb0.z + bflo(hv.y) * s;
    float a3 = bb0.w + bfhi(hv.y) * s;
    float a4 = bb1.x + bflo(hv.z) * s;
    float a5 = bb1.y + bfhi(hv.z) * s;
    float a6 = bb1.z + bflo(hv.w) * s;
    float a7 = bb1.w + bfhi(hv.w) * s;
    int j = offsets[c];
    const int end = offsets[c + 1];
    for (; j + 1 < end; j += 2) {
        int2 e0 = adjw[j], e1 = adjw[j + 1];
        uint4 v0 = *(const uint4*)(H + (size_t)e0.x * DIM + ql * 8);
        uint4 v1 = *(const uint4*)(H + (size_t)e1.x * DIM + ql * 8);
        float w0 = __int_as_float(e0.y), w1 = __int_as_float(e1.y);
        a0 += bflo(v0.x) * w0 + bflo(v1.x) * w1;
        a1 += bfhi(v0.x) * w0 + bfhi(v1.x) * w1;
        a2 += bflo(v0.y) * w0 + bflo(v1.y) * w1;
        a3 += bfhi(v0.y) * w0 + bfhi(v1.y) * w1;
        a4 += bflo(v0.z) * w0 + bflo(v1.z) * w1;
        a5 += bfhi(v0.z) * w0 + bfhi(v1.z) * w1;
        a6 += bflo(v0.w) * w0 + bflo(v1.w) * w1;
        a7 += bfhi(v0.w) * w0 + bfhi(v1.w) * w1;
    }
    if (j < end) {
        int2 e = adjw[j];
        uint4 v = *(const uint4*)(H + (size_t)e.x * DIM + ql * 8);
        float w = __int_as_float(e.y);
        a0 += bflo(v.x) * w;
        a1 += bfhi(v.x) * w;
        a2 += bflo(v.y) * w;
        a3 += bfhi(v.y) * w;
        a4 += bflo(v.z) * w;
        a5 += bfhi(v.z) * w;
        a6 += bflo(v.w) * w;
        a7 += bfhi(v.w) * w;
    }
    a0 = a0 > 0.f ? a0 : expf(a0) - 1.f;
    a1 = a1 > 0.f ? a1 : expf(a1) - 1.f;
    a2 = a2 > 0.f ? a2 : expf(a2) - 1.f;
    a3 = a3 > 0.f ? a3 : expf(a3) - 1.f;
    a4 = a4 > 0.f ? a4 : expf(a4) - 1.f;
    a5 = a5 > 0.f ? a5 : expf(a5) - 1.f;
    a6 = a6 > 0.f ? a6 : expf(a6) - 1.f;
    a7 = a7 > 0.f ? a7 : expf(a7) - 1.f;
    uint4 outv;
    outv.x = (unsigned int)f2bf(a0) | ((unsigned int)f2bf(a1) << 16);
    outv.y = (unsigned int)f2bf(a2) | ((unsigned int)f2bf(a3) << 16);
    outv.z = (unsigned int)f2bf(a4) | ((unsigned int)f2bf(a5) << 16);
    outv.w = (unsigned int)f2bf(a6) | ((unsigned int)f2bf(a7) << 16);
    *(uint4*)(AGG + (size_t)c * DIM + ql * 8) = outv;
}

// ---------------- quarter-wave agg + pool + fused final linear ----------------
// Each block: pooled partial (128 dims) -> 128x24 matvec -> 24 atomicAdds into out.
// out zeroed in k_init; block 0 adds lin_b.
__global__ __launch_bounds__(256) void k_aggpool2(const unsigned short* __restrict__ H,
                                                  const int* __restrict__ offsets,
                                                  const int2* __restrict__ adjw,
                                                  const float* __restrict__ dinv,
                                                  const float* __restrict__ b,
                                                  const float* __restrict__ lw,
                                                  const float* __restrict__ lb,
                                                  float* __restrict__ out, int n) {
    const int lane = threadIdx.x & 63;
    const int qw = lane >> 4, ql = lane & 15;
    const int wib = threadIdx.x >> 6;
    int p = (blockIdx.x * blockDim.x + threadIdx.x) >> 6;
    const int np = (gridDim.x * blockDim.x) >> 6;
    const int nquad = (n + 3) >> 2;
    const float4 bb0 = ((const float4*)b)[ql * 2];
    const float4 bb1 = ((const float4*)b)[ql * 2 + 1];
    float p0 = 0.f, p1 = 0.f, p2 = 0.f, p3 = 0.f, p4 = 0.f, p5 = 0.f, p6 = 0.f, p7 = 0.f;

    for (; p < nquad; p += np) {
        const int c = p * 4 + qw;
        if (c >= n) continue;
        float s = dinv[c];
        s = s * s;
        uint4 hv = *(const uint4*)(H + (size_t)c * DIM + ql * 8);
        float a0 = bb0.x + bflo(hv.x) * s;
        float a1 = bb0.y + bfhi(hv.x) * s;
        float a2 = bb0.z + bflo(hv.y) * s;
        float a3 = bb0.w + bfhi(hv.y) * s;
        float a4 = bb1.x + bflo(hv.z) * s;
        float a5 = bb1.y + bfhi(hv.z) * s;
        float a6 = bb1.z + bflo(hv.w) * s;
        float a7 = bb1.w + bfhi(hv.w) * s;
        int j = offsets[c];
        const int end = offsets[c + 1];
        for (; j + 1 < end; j += 2) {
            int2 e0 = adjw[j], e1 = adjw[j + 1];
            uint4 v0 = *(const uint4*)(H + (size_t)e0.x * DIM + ql * 8);
            uint4 v1 = *(const uint4*)(H + (size_t)e1.x * DIM + ql * 8);
            float w0 = __int_as_float(e0.y), w1 = __int_as_float(e1.y);
            a0 += bflo(v0.x) * w0 + bflo(v1.x) * w1;
            a1 += bfhi(v0.x) * w0 + bfhi(v1.x) * w1;
            a2 += bflo(v0.y) * w0 + bflo(v1.y) * w1;
            a3 += bfhi(v0.y) * w0 + bfhi(v1.y) * w1;
            a4 += bflo(v0.z) * w0 + bflo(v1.z) * w1;
            a5 += bfhi(v0.z) * w0 + bfhi(v1.z) * w1;
            a6 += bflo(v0.w) * w0 + bflo(v1.w) * w1;
            a7 += bfhi(v0.w) * w0 + bfhi(v1.w) * w1;
        }
        if (j < end) {
            int2 e = adjw[j];
            uint4 v = *(const uint4*)(H + (size_t)e.x * DIM + ql * 8);
            float w = __int_as_float(e.y);
            a0 += bflo(v.x) * w;
            a1 += bfhi(v.x) * w;
            a2 += bflo(v.y) * w;
            a3 += bfhi(v.y) * w;
            a4 += bflo(v.z) * w;
            a5 += bfhi(v.z) * w;
            a6 += bflo(v.w) * w;
            a7 += bfhi(v.w) * w;
        }
        p0 += a0 > 0.f ? a0 : expf(a0) - 1.f;
        p1 += a1 > 0.f ? a1 : expf(a1) - 1.f;
        p2 += a2 > 0.f ? a2 : expf(a2) - 1.f;
        p3 += a3 > 0.f ? a3 : expf(a3) - 1.f;
        p4 += a4 > 0.f ? a4 : expf(a4) - 1.f;
        p5 += a5 > 0.f ? a5 : expf(a5) - 1.f;
        p6 += a6 > 0.f ? a6 : expf(a6) - 1.f;
        p7 += a7 > 0.f ? a7 : expf(a7) - 1.f;
    }

    __shared__ float ps[16][DIM];
    *(float4*)&ps[wib * 4 + qw][ql * 8] = make_float4(p0, p1, p2, p3);
    *(float4*)&ps[wib * 4 + qw][ql * 8 + 4] = make_float4(p4, p5, p6, p7);
    __syncthreads();
    const int t = threadIdx.x;
    __shared__ float pooled[DIM];
    if (t < DIM) {
        float v = 0.f;
#pragma unroll
        for (int w = 0; w < 16; ++w) v += ps[w][t];
        pooled[t] = v;
    }
    __syncthreads();
    if (t < 24) {
        float acc = 0.f;
#pragma unroll 8
        for (int d = 0; d < DIM; ++d) acc += pooled[d] * lw[d * 24 + t];
        acc *= (1.0f / (float)NN);
        if (blockIdx.x == 0) acc += lb[t];
        atomicAdd(&out[t], acc);
    }
}

extern "C" void kernel_launch(void* const* d_in, const int* in_sizes, int n_in,
                              void* d_out, int out_size, void* d_ws, size_t ws_size,
                              hipStream_t stream) {
    const float* x  = (const float*)d_in[0];
    const int*   ei = (const int*)d_in[1];
    const float* W0 = (const float*)d_in[2];
    const float* b0 = (const float*)d_in[3];
    const float* W1 = (const float*)d_in[4];
    const float* b1 = (const float*)d_in[5];
    const float* W2 = (const float*)d_in[6];
    const float* b2 = (const float*)d_in[7];
    const float* lw = (const float*)d_in[8];
    const float* lb = (const float*)d_in[9];
    float* out = (float*)d_out;

    const int N = NN, E = NE;
    const int* rows = ei;        // sources (gather)
    const int* cols = ei + E;    // targets (aggregate)

    char* ws = (char*)d_ws;
    unsigned short* H   = (unsigned short*)ws;                      // 25,600,000 B
    unsigned short* AGG = (unsigned short*)(ws + 25600000);         // 25,600,000 B
    float* dinv    = (float*)(ws + 51200000);                       // 400,000 B
    int*   offsets = (int*)(ws + 51600512);                         // 400,128 B (N+1)
    int*   cursor  = (int*)(ws + 52000640);                         // 400,000 B
    int*   segsum  = (int*)(ws + 52400640);                         // 512 B slot
    int2*  adjw    = (int2*)(ws + 52401152);                        // 4,800,000 B
    unsigned short* Wp = (unsigned short*)(ws + 57201152);          // 3 x 32,768 B
    // (partials buffer retired — final linear fused into k_aggpool2)

    const int agg_grid = (N + 15) / 16;    // quarter-wave: 16 nodes/block
    const int gemm_grid = (N + 63) / 64;   // 1563

    // CSR build + weight pack (unpacked — R13 hybrids were latency-bound mixtures)
    k_init<<<291, 256, 0, stream>>>(offsets, W0, W1, W2, Wp, out);
    k_hist<<<(E / 2 + 255) / 256, 256, 0, stream>>>(cols, offsets, E);
    k_scan1<<<NSEG, 256, 0, stream>>>(offsets, segsum, dinv, N);
    k_scan23<<<NSEG, 256, 0, stream>>>(offsets, segsum, cursor, N);
    k_fill<<<(E + 255) / 256, 256, 0, stream>>>(rows, cols, dinv, cursor, adjw, E);
    // layer 0 GEMM (standalone)
    k_gemm0<<<gemm_grid, 256, 0, stream>>>(x, Wp, H, N);

    // layer 0 agg
    k_agg2<<<agg_grid, 256, 0, stream>>>(H, offsets, adjw, dinv, b0, AGG, N);
    // layer 1
    k_gemm<<<gemm_grid, 256, 0, stream>>>(AGG, Wp + 16384, H, N);
    k_agg2<<<agg_grid, 256, 0, stream>>>(H, offsets, adjw, dinv, b1, AGG, N);
    // layer 2 (pool + final linear fused)
    k_gemm<<<gemm_grid, 256, 0, stream>>>(AGG, Wp + 32768, H, N);
    k_aggpool2<<<PBLK, 256, 0, stream>>>(H, offsets, adjw, dinv, b2, lw, lb, out, N);
}

// Round 15
// 295.104 us; speedup vs baseline: 1.0916x; 1.0916x over previous
//
#include <hip/hip_runtime.h>
#include <math.h>

#define NN 100000
#define NE 600000
#define DIM 128
#define SEG 1024
#define NSEG 98    // ceil(100000/1024)
#define PBLK 2048  // pooled-agg grid
#define G0A 782    // gemm0 tiles packed with count
#define G0B 781    // gemm0 tiles packed with fill (G0A+G0B = 1563 = ceil(N/64))
#define CNTB 2344  // ceil(NE/256)

typedef __attribute__((ext_vector_type(8))) short short8;
typedef __attribute__((ext_vector_type(4))) float floatx4;

// bf16 helpers (RNE)
static __device__ __forceinline__ unsigned short f2bf(float f) {
    union { float f; unsigned u; } v; v.f = f;
    unsigned r = v.u + 0x7fffu + ((v.u >> 16) & 1u);
    return (unsigned short)(r >> 16);
}
static __device__ __forceinline__ float bflo(unsigned int p) {
    union { unsigned u; float f; } v; v.u = p << 16; return v.f;
}
static __device__ __forceinline__ float bfhi(unsigned int p) {
    union { unsigned u; float f; } v; v.u = p & 0xffff0000u; return v.f;
}

// ---------------- MFMA GEMM tile (R10 staged version: LDS coalesced staging) ----------------
template <bool A_IS_F32>
static __device__ void gemm_tile(const void* __restrict__ Ain,
                                 const unsigned short* __restrict__ Wp,
                                 unsigned short* __restrict__ H, int n, int tb) {
    __shared__ __align__(16) unsigned short As[64][136];
    const int t = threadIdx.x;
    const int wid = t >> 6, lane = t & 63;
    const int wy = wid & 1, wx = wid >> 1;
    const int base = tb * 64;

    short8 Bf[4][4];
    {
        const short8* wp8 = (const short8*)Wp;
#pragma unroll
        for (int tt = 0; tt < 4; ++tt)
#pragma unroll
            for (int kk = 0; kk < 4; ++kk)
                Bf[tt][kk] = wp8[(((wx * 4 + tt) * 4 + kk) * 64) + lane];
    }

    if constexpr (A_IS_F32) {
        const float* A = (const float*)Ain;
#pragma unroll
        for (int it = 0; it < 8; ++it) {
            int idx = it * 256 + t;
            int row = idx >> 5, seg = idx & 31;
            int r = base + row;
            float4 v = make_float4(0.f, 0.f, 0.f, 0.f);
            if (r < n) v = ((const float4*)(A + (size_t)r * DIM))[seg];
            ushort4 o;
            o.x = f2bf(v.x); o.y = f2bf(v.y); o.z = f2bf(v.z); o.w = f2bf(v.w);
            *((ushort4*)&As[row][seg * 4]) = o;
        }
    } else {
        const unsigned short* A = (const unsigned short*)Ain;
#pragma unroll
        for (int it = 0; it < 4; ++it) {
            int idx = it * 256 + t;
            int row = idx >> 4, seg = idx & 15;
            int r = base + row;
            uint4 v = make_uint4(0, 0, 0, 0);
            if (r < n) v = ((const uint4*)(A + (size_t)r * DIM))[seg];
            *((uint4*)&As[row][seg * 8]) = v;
        }
    }
    __syncthreads();

    floatx4 acc[2][4];
#pragma unroll
    for (int rs = 0; rs < 2; ++rs)
#pragma unroll
        for (int tt = 0; tt < 4; ++tt) acc[rs][tt] = (floatx4){0.f, 0.f, 0.f, 0.f};

    const int m = lane & 15, q = lane >> 4;
#pragma unroll
    for (int rs = 0; rs < 2; ++rs) {
        const int rbase = wy * 32 + rs * 16 + m;
        short8 Af[4];
#pragma unroll
        for (int kk = 0; kk < 4; ++kk)
            Af[kk] = *((const short8*)&As[rbase][kk * 32 + q * 8]);
#pragma unroll
        for (int kk = 0; kk < 4; ++kk)
#pragma unroll
            for (int tt = 0; tt < 4; ++tt)
                acc[rs][tt] = __builtin_amdgcn_mfma_f32_16x16x32_bf16(Af[kk], Bf[tt][kk],
                                                                     acc[rs][tt], 0, 0, 0);
    }
    __syncthreads();

#pragma unroll
    for (int rs = 0; rs < 2; ++rs)
#pragma unroll
        for (int tt = 0; tt < 4; ++tt) {
            const int col = wx * 64 + tt * 16 + m;
            const int rowb = wy * 32 + rs * 16 + q * 4;
#pragma unroll
            for (int i = 0; i < 4; ++i)
                As[rowb + i][col] = f2bf(acc[rs][tt][i]);
        }
    __syncthreads();
#pragma unroll
    for (int it = 0; it < 4; ++it) {
        int idx = it * 256 + t;
        int row = idx >> 4, seg = idx & 15;
        int r = base + row;
        if (r < n)
            ((uint4*)(H + (size_t)r * DIM))[seg] = *((const uint4*)&As[row][seg * 8]);
    }
}

// ---------------- K_init: zero counts, pack W0/W1/W2 ----------------
__global__ __launch_bounds__(256) void k_init(int* __restrict__ counts,
                                              const float* __restrict__ W0,
                                              const float* __restrict__ W1,
                                              const float* __restrict__ W2,
                                              unsigned short* __restrict__ Wp) {
    const int bid = blockIdx.x, t = threadIdx.x;
    if (bid < 99) {
        const int base = bid * 1024 + t * 4;
#pragma unroll
        for (int i = 0; i < 4; ++i)
            if (base + i < NN + 1) counts[base + i] = 0;
    } else {
        const int wb = bid - 99;
        const int which = wb >> 6;
        const float* W = which == 0 ? W0 : (which == 1 ? W1 : W2);
        unsigned short* dst = Wp + which * 16384;
        int e = (wb & 63) * 256 + t;
        int j  = e & 7;
        int L  = (e >> 3) & 63;
        int kk = (e >> 9) & 3;
        int ct = e >> 11;
        int k = kk * 32 + (L >> 4) * 8 + j;
        int c = ct * 16 + (L & 15);
        dst[e] = f2bf(W[k * DIM + c]);
    }
}

// ---------------- gemm0 tiles [0,G0A) packed with edge histogram ----------------
__global__ __launch_bounds__(256) void k_g0count(const float* __restrict__ x,
                                                 const unsigned short* __restrict__ Wp,
                                                 unsigned short* __restrict__ H,
                                                 const int* __restrict__ col,
                                                 int* __restrict__ counts, int n, int E) {
    if (blockIdx.x < G0A) {
        gemm_tile<true>((const void*)x, Wp, H, n, blockIdx.x);
    } else {
        int i = (blockIdx.x - G0A) * 256 + threadIdx.x;
        if (i < E) atomicAdd(&counts[col[i]], 1);
    }
}

// ---------------- scan phase 1 + fused dinv ----------------
__global__ __launch_bounds__(256) void k_scan1(int* __restrict__ data, int* __restrict__ segsum,
                                               float* __restrict__ dinv, int n) {
    __shared__ int s[256];
    const int t = threadIdx.x;
    const int base = blockIdx.x * SEG + t * 4;
    int v[4];
#pragma unroll
    for (int i = 0; i < 4; ++i) v[i] = (base + i < n) ? data[base + i] : 0;
#pragma unroll
    for (int i = 0; i < 4; ++i)
        if (base + i < n) dinv[base + i] = rsqrtf((float)v[i] + 1.0f);
    int tsum = v[0] + v[1] + v[2] + v[3];
    s[t] = tsum;
    __syncthreads();
    for (int off = 1; off < 256; off <<= 1) {
        int x = (t >= off) ? s[t - off] : 0;
        __syncthreads();
        s[t] += x;
        __syncthreads();
    }
    int run = s[t] - tsum;
#pragma unroll
    for (int i = 0; i < 4; ++i) {
        if (base + i < n) data[base + i] = run;
        run += v[i];
    }
    if (t == 255) segsum[blockIdx.x] = s[255];
}

// ---------------- scan phases 2+3 merged ----------------
__global__ __launch_bounds__(256) void k_scan23(int* __restrict__ offsets,
                                                const int* __restrict__ segsum,
                                                int* __restrict__ cursor, int n) {
    __shared__ int ss[NSEG];
    __shared__ int myoff_s, total_s;
    const int t = threadIdx.x;
    if (t < NSEG) ss[t] = segsum[t];
    __syncthreads();
    if (t == 0) {
        int run = 0;
#pragma unroll 7
        for (int i = 0; i < NSEG; ++i) {
            if (i == (int)blockIdx.x) myoff_s = run;
            run += ss[i];
        }
        total_s = run;
    }
    __syncthreads();
    const int so = myoff_s;
    const int base = blockIdx.x * SEG + t * 4;
#pragma unroll
    for (int i = 0; i < 4; ++i) {
        if (base + i < n) {
            int o = offsets[base + i] + so;
            offsets[base + i] = o;
            cursor[base + i] = o;
        }
    }
    if (blockIdx.x == 0 && t == 0) offsets[n] = total_s;
}

// ---------------- gemm0 tiles [G0A,G0A+G0B) packed with CSR fill ----------------
__global__ __launch_bounds__(256) void k_g0fill(const float* __restrict__ x,
                                                const unsigned short* __restrict__ Wp,
                                                unsigned short* __restrict__ H,
                                                const int* __restrict__ rows,
                                                const int* __restrict__ cols,
                                                const float* __restrict__ dinv,
                                                int* __restrict__ cursor,
                                                int2* __restrict__ adjw, int n, int E) {
    if (blockIdx.x < G0B) {
        gemm_tile<true>((const void*)x, Wp, H, n, G0A + blockIdx.x);
    } else {
        int e = (blockIdx.x - G0B) * 256 + threadIdx.x;
        if (e < E) {
            int r = rows[e];
            int c = cols[e];
            int pos = atomicAdd(&cursor[c], 1);
            adjw[pos] = make_int2(r, __float_as_int(dinv[r] * dinv[c]));
        }
    }
}

// ---------------- standalone GEMM (layers 1,2) ----------------
__global__ __launch_bounds__(256) void k_gemm(const unsigned short* __restrict__ A,
                                              const unsigned short* __restrict__ Wp,
                                              unsigned short* __restrict__ H, int n) {
    gemm_tile<false>((const void*)A, Wp, H, n, blockIdx.x);
}

// ---------------- quarter-wave-per-node CSR aggregation (self + bias + ELU) ----------------
// 16 lanes/node, uint4 (16B) per lane -> full 256B row coalescing; 4 node streams/wave
// x unroll-2 = 8 outstanding row gathers with finer degree-imbalance averaging.
__global__ __launch_bounds__(256) void k_agg2(const unsigned short* __restrict__ H,
                                              const int* __restrict__ offsets,
                                              const int2* __restrict__ adjw,
                                              const float* __restrict__ dinv,
                                              const float* __restrict__ b,
                                              unsigned short* __restrict__ AGG, int n) {
    const int lane = threadIdx.x & 63;
    const int qw = lane >> 4, ql = lane & 15;
    const int p = (blockIdx.x * blockDim.x + threadIdx.x) >> 6;
    const int c = p * 4 + qw;
    if (c >= n) return;
    const float4 bb0 = ((const float4*)b)[ql * 2];
    const float4 bb1 = ((const float4*)b)[ql * 2 + 1];
    float s = dinv[c];
    s = s * s;
    uint4 hv = *(const uint4*)(H + (size_t)c * DIM + ql * 8);
    float a0 = bb0.x + bflo(hv.x) * s;
    float a1 = bb0.y + bfhi(hv.x) * s;
    float a2 = bb0.z + bflo(hv.y) * s;
    float a3 = bb0.w + bfhi(hv.y) * s;
    float a4 = bb1.x + bflo(hv.z) * s;
    float a5 = bb1.y + bfhi(hv.z) * s;
    float a6 = bb1.z + bflo(hv.w) * s;
    float a7 = bb1.w + bfhi(hv.w) * s;
    int j = offsets[c];
    const int end = offsets[c + 1];
    for (; j + 1 < end; j += 2) {
        int2 e0 = adjw[j], e1 = adjw[j + 1];
        uint4 v0 = *(const uint4*)(H + (size_t)e0.x * DIM + ql * 8);
        uint4 v1 = *(const uint4*)(H + (size_t)e1.x * DIM + ql * 8);
        float w0 = __int_as_float(e0.y), w1 = __int_as_float(e1.y);
        a0 += bflo(v0.x) * w0 + bflo(v1.x) * w1;
        a1 += bfhi(v0.x) * w0 + bfhi(v1.x) * w1;
        a2 += bflo(v0.y) * w0 + bflo(v1.y) * w1;
        a3 += bfhi(v0.y) * w0 + bfhi(v1.y) * w1;
        a4 += bflo(v0.z) * w0 + bflo(v1.z) * w1;
        a5 += bfhi(v0.z) * w0 + bfhi(v1.z) * w1;
        a6 += bflo(v0.w) * w0 + bflo(v1.w) * w1;
        a7 += bfhi(v0.w) * w0 + bfhi(v1.w) * w1;
    }
    if (j < end) {
        int2 e = adjw[j];
        uint4 v = *(const uint4*)(H + (size_t)e.x * DIM + ql * 8);
        float w = __int_as_float(e.y);
        a0 += bflo(v.x) * w;
        a1 += bfhi(v.x) * w;
        a2 += bflo(v.y) * w;
        a3 += bfhi(v.y) * w;
        a4 += bflo(v.z) * w;
        a5 += bfhi(v.z) * w;
        a6 += bflo(v.w) * w;
        a7 += bfhi(v.w) * w;
    }
    a0 = a0 > 0.f ? a0 : expf(a0) - 1.f;
    a1 = a1 > 0.f ? a1 : expf(a1) - 1.f;
    a2 = a2 > 0.f ? a2 : expf(a2) - 1.f;
    a3 = a3 > 0.f ? a3 : expf(a3) - 1.f;
    a4 = a4 > 0.f ? a4 : expf(a4) - 1.f;
    a5 = a5 > 0.f ? a5 : expf(a5) - 1.f;
    a6 = a6 > 0.f ? a6 : expf(a6) - 1.f;
    a7 = a7 > 0.f ? a7 : expf(a7) - 1.f;
    uint4 outv;
    outv.x = (unsigned int)f2bf(a0) | ((unsigned int)f2bf(a1) << 16);
    outv.y = (unsigned int)f2bf(a2) | ((unsigned int)f2bf(a3) << 16);
    outv.z = (unsigned int)f2bf(a4) | ((unsigned int)f2bf(a5) << 16);
    outv.w = (unsigned int)f2bf(a6) | ((unsigned int)f2bf(a7) << 16);
    *(uint4*)(AGG + (size_t)c * DIM + ql * 8) = outv;
}

// ---------------- quarter-wave agg + pooling (layer 2 epilogue) ----------------
// partials written TRANSPOSED: partials[d * PBLK + blockIdx.x]; block 0 zeroes out[]
__global__ __launch_bounds__(256) void k_aggpool2(const unsigned short* __restrict__ H,
                                                  const int* __restrict__ offsets,
                                                  const int2* __restrict__ adjw,
                                                  const float* __restrict__ dinv,
                                                  const float* __restrict__ b,
                                                  float* __restrict__ partials,
                                                  float* __restrict__ out, int n) {
    if (blockIdx.x == 0 && threadIdx.x < 24) out[threadIdx.x] = 0.f;  // pre-zero for atomic epilogue
    const int lane = threadIdx.x & 63;
    const int qw = lane >> 4, ql = lane & 15;
    const int wib = threadIdx.x >> 6;
    int p = (blockIdx.x * blockDim.x + threadIdx.x) >> 6;
    const int np = (gridDim.x * blockDim.x) >> 6;
    const int nquad = (n + 3) >> 2;
    const float4 bb0 = ((const float4*)b)[ql * 2];
    const float4 bb1 = ((const float4*)b)[ql * 2 + 1];
    float p0 = 0.f, p1 = 0.f, p2 = 0.f, p3 = 0.f, p4 = 0.f, p5 = 0.f, p6 = 0.f, p7 = 0.f;

    for (; p < nquad; p += np) {
        const int c = p * 4 + qw;
        if (c >= n) continue;
        float s = dinv[c];
        s = s * s;
        uint4 hv = *(const uint4*)(H + (size_t)c * DIM + ql * 8);
        float a0 = bb0.x + bflo(hv.x) * s;
        float a1 = bb0.y + bfhi(hv.x) * s;
        float a2 = bb0.z + bflo(hv.y) * s;
        float a3 = bb0.w + bfhi(hv.y) * s;
        float a4 = bb1.x + bflo(hv.z) * s;
        float a5 = bb1.y + bfhi(hv.z) * s;
        float a6 = bb1.z + bflo(hv.w) * s;
        float a7 = bb1.w + bfhi(hv.w) * s;
        int j = offsets[c];
        const int end = offsets[c + 1];
        for (; j + 1 < end; j += 2) {
            int2 e0 = adjw[j], e1 = adjw[j + 1];
            uint4 v0 = *(const uint4*)(H + (size_t)e0.x * DIM + ql * 8);
            uint4 v1 = *(const uint4*)(H + (size_t)e1.x * DIM + ql * 8);
            float w0 = __int_as_float(e0.y), w1 = __int_as_float(e1.y);
            a0 += bflo(v0.x) * w0 + bflo(v1.x) * w1;
            a1 += bfhi(v0.x) * w0 + bfhi(v1.x) * w1;
            a2 += bflo(v0.y) * w0 + bflo(v1.y) * w1;
            a3 += bfhi(v0.y) * w0 + bfhi(v1.y) * w1;
            a4 += bflo(v0.z) * w0 + bflo(v1.z) * w1;
            a5 += bfhi(v0.z) * w0 + bfhi(v1.z) * w1;
            a6 += bflo(v0.w) * w0 + bflo(v1.w) * w1;
            a7 += bfhi(v0.w) * w0 + bfhi(v1.w) * w1;
        }
        if (j < end) {
            int2 e = adjw[j];
            uint4 v = *(const uint4*)(H + (size_t)e.x * DIM + ql * 8);
            float w = __int_as_float(e.y);
            a0 += bflo(v.x) * w;
            a1 += bfhi(v.x) * w;
            a2 += bflo(v.y) * w;
            a3 += bfhi(v.y) * w;
            a4 += bflo(v.z) * w;
            a5 += bfhi(v.z) * w;
            a6 += bflo(v.w) * w;
            a7 += bfhi(v.w) * w;
        }
        p0 += a0 > 0.f ? a0 : expf(a0) - 1.f;
        p1 += a1 > 0.f ? a1 : expf(a1) - 1.f;
        p2 += a2 > 0.f ? a2 : expf(a2) - 1.f;
        p3 += a3 > 0.f ? a3 : expf(a3) - 1.f;
        p4 += a4 > 0.f ? a4 : expf(a4) - 1.f;
        p5 += a5 > 0.f ? a5 : expf(a5) - 1.f;
        p6 += a6 > 0.f ? a6 : expf(a6) - 1.f;
        p7 += a7 > 0.f ? a7 : expf(a7) - 1.f;
    }

    __shared__ float ps[16][DIM];
    *(float4*)&ps[wib * 4 + qw][ql * 8] = make_float4(p0, p1, p2, p3);
    *(float4*)&ps[wib * 4 + qw][ql * 8 + 4] = make_float4(p4, p5, p6, p7);
    __syncthreads();
    const int t = threadIdx.x;
    if (t < DIM) {
        float v = 0.f;
#pragma unroll
        for (int w = 0; w < 16; ++w) v += ps[w][t];
        partials[(size_t)t * PBLK + blockIdx.x] = v;   // transposed
    }
}

// ---------------- per-dim reduce + distributed atomic final linear ----------------
__global__ __launch_bounds__(256) void k_pool2final(const float* __restrict__ partials,
                                                    const float* __restrict__ lw,
                                                    const float* __restrict__ lb,
                                                    float* __restrict__ out) {
    const int d = blockIdx.x;           // 128 blocks, one per dim; row is contiguous
    const float4* row = (const float4*)(partials + (size_t)d * PBLK);
    float acc = 0.f;
#pragma unroll
    for (int i = 0; i < PBLK / 4 / 256; ++i) {
        float4 v = row[i * 256 + threadIdx.x];
        acc += v.x + v.y + v.z + v.w;
    }
#pragma unroll
    for (int off = 32; off; off >>= 1) acc += __shfl_down(acc, off, 64);
    __shared__ float wsum[4];
    if ((threadIdx.x & 63) == 0) wsum[threadIdx.x >> 6] = acc;
    __syncthreads();
    if (threadIdx.x < 24) {
        float pooled_d = wsum[0] + wsum[1] + wsum[2] + wsum[3];
        float contrib = pooled_d * lw[d * 24 + threadIdx.x] * (1.0f / (float)NN);
        if (d == 0) contrib += lb[threadIdx.x];
        atomicAdd(&out[threadIdx.x], contrib);
    }
}

extern "C" void kernel_launch(void* const* d_in, const int* in_sizes, int n_in,
                              void* d_out, int out_size, void* d_ws, size_t ws_size,
                              hipStream_t stream) {
    const float* x  = (const float*)d_in[0];
    const int*   ei = (const int*)d_in[1];
    const float* W0 = (const float*)d_in[2];
    const float* b0 = (const float*)d_in[3];
    const float* W1 = (const float*)d_in[4];
    const float* b1 = (const float*)d_in[5];
    const float* W2 = (const float*)d_in[6];
    const float* b2 = (const float*)d_in[7];
    const float* lw = (const float*)d_in[8];
    const float* lb = (const float*)d_in[9];
    float* out = (float*)d_out;

    const int N = NN, E = NE;
    const int* rows = ei;        // sources (gather)
    const int* cols = ei + E;    // targets (aggregate)

    char* ws = (char*)d_ws;
    unsigned short* H   = (unsigned short*)ws;                      // 25,600,000 B
    unsigned short* AGG = (unsigned short*)(ws + 25600000);         // 25,600,000 B
    float* dinv    = (float*)(ws + 51200000);                       // 400,000 B
    int*   offsets = (int*)(ws + 51600512);                         // 400,128 B (N+1)
    int*   cursor  = (int*)(ws + 52000640);                         // 400,000 B
    int*   segsum  = (int*)(ws + 52400640);                         // 512 B slot
    int2*  adjw    = (int2*)(ws + 52401152);                        // 4,800,000 B
    unsigned short* Wp = (unsigned short*)(ws + 57201152);          // 3 x 32,768 B
    float* partials = (float*)(ws + 57299456);                      // 1,048,576 B

    const int agg_grid = (N + 15) / 16;    // 16 nodes per 256-thread block (quarter-wave)
    const int gemm_grid = (N + 63) / 64;   // 1563 = G0A + G0B

    // init: zero counts, pack weights                   [independent of everything]
    k_init<<<291, 256, 0, stream>>>(offsets, W0, W1, W2, Wp);
    // gemm0 (1st half) packed with edge histogram
    k_g0count<<<G0A + CNTB, 256, 0, stream>>>(x, Wp, H, cols, offsets, N, E);
    // scan
    k_scan1<<<NSEG, 256, 0, stream>>>(offsets, segsum, dinv, N);
    k_scan23<<<NSEG, 256, 0, stream>>>(offsets, segsum, cursor, N);
    // gemm0 (2nd half) packed with CSR fill
    k_g0fill<<<G0B + CNTB, 256, 0, stream>>>(x, Wp, H, rows, cols, dinv, cursor, adjw, N, E);

    // layer 0 agg
    k_agg2<<<agg_grid, 256, 0, stream>>>(H, offsets, adjw, dinv, b0, AGG, N);
    // layer 1
    k_gemm<<<gemm_grid, 256, 0, stream>>>(AGG, Wp + 16384, H, N);
    k_agg2<<<agg_grid, 256, 0, stream>>>(H, offsets, adjw, dinv, b1, AGG, N);
    // layer 2 (pooling fused)
    k_gemm<<<gemm_grid, 256, 0, stream>>>(AGG, Wp + 32768, H, N);
    k_aggpool2<<<PBLK, 256, 0, stream>>>(H, offsets, adjw, dinv, b2, partials, out, N);

    k_pool2final<<<DIM, 256, 0, stream>>>(partials, lw, lb, out);
}